// Round 8
// baseline (219.649 us; speedup 1.0000x reference)
//
#include <hip/hip_runtime.h>
#include <cmath>

namespace {

constexpr int BATCH = 256;
// layer 1
constexpr int C1 = 3, H1 = 218, W1 = 178;
constexpr int IMG1 = C1 * H1 * W1;            // 116412
constexpr int PLANE1 = H1 * W1;               // 38804
constexpr int O1 = 8, HO1 = 54, WO1 = 44;
constexpr int HW1 = HO1 * WO1;                // 2376
constexpr int P1 = C1 * 36;                   // 108
// layer 2
constexpr int C2 = 8, H2c = 54, W2c = 44;
constexpr int IMG2 = C2 * H2c * W2c;          // 19008
constexpr int PLANE2 = H2c * W2c;             // 2376
constexpr int O2 = 16, HO2 = 13, WO2 = 10;
constexpr int HW2 = HO2 * WO2;                // 130
constexpr int P2 = C2 * 36;                   // 288
// head
constexpr int NPOOL = 480;                    // 16*6*5
constexpr int N1 = 300, N2 = 200;

// lc1 tiling: block = (1 ho row x 44 wo x 8 o) x 8 batches, 192 threads.
constexpr int NB1 = 8;                        // batches per block
constexpr int XROW = 180;                     // padded LDS row (178 + 2) keeps float4 row base 16B-aligned
constexpr int XCHUNK = NB1 * XROW;            // 1440 floats per x chunk buffer
constexpr int WCHUNK = 2 * 6 * 44 * 4;        // 2112 floats per w chunk buffer ([oh][kw][wo][4])

// ---- transpose w1 (O1,P1,HW1) -> (P1*HW1, O1)
__global__ __launch_bounds__(256) void wt1_kernel(const float* __restrict__ w,
                                                  float* __restrict__ wt) {
  const int idx = blockIdx.x * 256 + threadIdx.x;   // p*HW1 + hw
  if (idx >= P1 * HW1) return;
  float v[O1];
#pragma unroll
  for (int o = 0; o < O1; ++o) v[o] = w[(size_t)o * (P1 * HW1) + idx];
  float4* dst = reinterpret_cast<float4*>(wt + (size_t)idx * O1);
  dst[0] = make_float4(v[0], v[1], v[2], v[3]);
  dst[1] = make_float4(v[4], v[5], v[6], v[7]);
}

// ---- transpose w2 (O2,P2,HW2) -> (P2*HW2, O2)
__global__ __launch_bounds__(256) void wt2_kernel(const float* __restrict__ w,
                                                  float* __restrict__ wt) {
  const int idx = blockIdx.x * 256 + threadIdx.x;   // p*HW2 + hw
  if (idx >= P2 * HW2) return;
  float v[O2];
#pragma unroll
  for (int o = 0; o < O2; ++o) v[o] = w[(size_t)o * (P2 * HW2) + idx];
  float4* dst = reinterpret_cast<float4*>(wt + (size_t)idx * O2);
  dst[0] = make_float4(v[0], v[1], v[2], v[3]);
  dst[1] = make_float4(v[4], v[5], v[6], v[7]);
  dst[2] = make_float4(v[8], v[9], v[10], v[11]);
  dst[3] = make_float4(v[12], v[13], v[14], v[15]);
}

// ---- locally-connected layer 1 + ReLU, fully LDS-staged.
// Evidence (rounds 2-7): time ~96-109us invariant to occupancy/VGPR/load
// clustering -> bound by the global access pattern itself (strided float4
// w-reads = 16 lines/instr, tiny x windows). Fix = lc2's recipe: bulk
// coalesced staging into LDS chunks (contiguous rows/runs), double-buffered,
// inner loop reads LDS only. Block = (ho row, 8 batches), 192 threads.
__global__ __launch_bounds__(192) void lc1_kernel(const float* __restrict__ x,
                                                  const float* __restrict__ w1t,
                                                  const float* __restrict__ b1,
                                                  float* __restrict__ h1) {
  __shared__ __align__(16) float xlds[2][XCHUNK];   // 11520 B
  __shared__ __align__(16) float wlds[2][WCHUNK];   // 16896 B
  const int t = threadIdx.x;
  const int ho = blockIdx.x;
  const int bg = blockIdx.y * NB1;

  const int b2 = t / 44;              // 0..3 for t<176 (compute-active)
  const int wo = t - b2 * 44;
  const bool act = t < 176;

  float acc[2][O1];
  if (act) {
    const int hw = ho * WO1 + wo;
#pragma unroll
    for (int o = 0; o < O1; ++o) {
      const float bv = b1[o * HW1 + hw];
      acc[0][o] = bv;
      acc[1][o] = bv;
    }
  }

  // ---------- staging helpers (manually inlined: load phase / write phase)
  float2 xr[4];
  float4 wr4[3];

#define STAGE_LOAD(K)                                                          \
  do {                                                                         \
    const int c_ = (K) / 6, kh_ = (K) - c_ * 6;                                \
    const int row_ = ho * 4 + kh_;                                             \
    _Pragma("unroll") for (int s = 0; s < 4; ++s) {                            \
      int i = t + s * 192; i = i < 711 ? i : 711;                              \
      const int b_ = i / 89, c2_ = i - b_ * 89;                                \
      xr[s] = *reinterpret_cast<const float2*>(                                \
          x + ((size_t)(bg + b_) * C1 + c_) * PLANE1 + (size_t)row_ * W1 +     \
          c2_ * 2);                                                            \
    }                                                                          \
    const size_t wbase_ = ((size_t)((K) * 6) * HW1 + ho * WO1) * 8;            \
    _Pragma("unroll") for (int s = 0; s < 3; ++s) {                            \
      int i = t + s * 192; i = i < 527 ? i : 527;                              \
      const int kw_ = i / 88, r_ = i - kw_ * 88;                               \
      wr4[s] = *reinterpret_cast<const float4*>(                               \
          w1t + wbase_ + (size_t)kw_ * (HW1 * 8) + r_ * 4);                    \
    }                                                                          \
  } while (0)

#define STAGE_WRITE(BUF)                                                       \
  do {                                                                         \
    _Pragma("unroll") for (int s = 0; s < 4; ++s) {                            \
      int i = t + s * 192; i = i < 711 ? i : 711;                              \
      const int b_ = i / 89, c2_ = i - b_ * 89;                                \
      *reinterpret_cast<float2*>(&xlds[BUF][b_ * XROW + c2_ * 2]) = xr[s];     \
    }                                                                          \
    _Pragma("unroll") for (int s = 0; s < 3; ++s) {                            \
      int i = t + s * 192; i = i < 527 ? i : 527;                              \
      const int kw_ = i / 88, r_ = i - kw_ * 88;                               \
      reinterpret_cast<float4*>(wlds[BUF])[((r_ & 1) * 6 + kw_) * 44 +         \
                                           (r_ >> 1)] = wr4[s];                \
    }                                                                          \
  } while (0)

  // prologue: stage chunk 0
  STAGE_LOAD(0);
  STAGE_WRITE(0);

#pragma unroll 1
  for (int k = 0; k < 18; ++k) {
    __syncthreads();                    // buf (k&1) ready for all waves
    // T14 split: issue next chunk's global loads first, hide under compute
    if (k < 17) STAGE_LOAD(k + 1);

    if (act) {
      const float* xb = xlds[k & 1];
      const float4* wb = reinterpret_cast<const float4*>(wlds[k & 1]);
      float xw[2][6];
#pragma unroll
      for (int jj = 0; jj < 2; ++jj) {
        const int xoff = (b2 * 2 + jj) * XROW + wo * 4;
        const float4 xa = *reinterpret_cast<const float4*>(&xb[xoff]);
        const float2 xt = *reinterpret_cast<const float2*>(&xb[xoff + 4]);
        xw[jj][0] = xa.x; xw[jj][1] = xa.y; xw[jj][2] = xa.z; xw[jj][3] = xa.w;
        xw[jj][4] = xt.x; xw[jj][5] = xt.y;
      }
#pragma unroll
      for (int kw = 0; kw < 6; ++kw) {
        const float4 w0 = wb[kw * 44 + wo];
        const float4 w1v = wb[(6 + kw) * 44 + wo];
#pragma unroll
        for (int jj = 0; jj < 2; ++jj) {
          const float xs = xw[jj][kw];
          acc[jj][0] = fmaf(xs, w0.x, acc[jj][0]);
          acc[jj][1] = fmaf(xs, w0.y, acc[jj][1]);
          acc[jj][2] = fmaf(xs, w0.z, acc[jj][2]);
          acc[jj][3] = fmaf(xs, w0.w, acc[jj][3]);
          acc[jj][4] = fmaf(xs, w1v.x, acc[jj][4]);
          acc[jj][5] = fmaf(xs, w1v.y, acc[jj][5]);
          acc[jj][6] = fmaf(xs, w1v.z, acc[jj][6]);
          acc[jj][7] = fmaf(xs, w1v.w, acc[jj][7]);
        }
      }
    }

    if (k < 17) {
      __syncthreads();                  // everyone done reading buf ((k+1)&1)
      STAGE_WRITE((k + 1) & 1);
    }
  }
#undef STAGE_LOAD
#undef STAGE_WRITE

  if (act) {
#pragma unroll
    for (int jj = 0; jj < 2; ++jj) {
      const int b = bg + b2 * 2 + jj;
      float* op = h1 + (size_t)b * (O1 * HW1) + ho * WO1 + wo;
#pragma unroll
      for (int o = 0; o < O1; ++o) op[(size_t)o * HW1] = fmaxf(acc[jj][o], 0.f);
    }
  }
}

// ---- locally-connected layer 2 + ReLU, GEMM-ified per spatial location.
__global__ __launch_bounds__(256) void lc2_kernel(const float* __restrict__ h1,
                                                  const float* __restrict__ w2t,
                                                  const float* __restrict__ b2,
                                                  float* __restrict__ h2) {
  __shared__ float ws[P2 * O2];                 // 18432 B
  const int hw = blockIdx.x;
  const int lane = threadIdx.x & 63;
  const int og = threadIdx.x >> 6;
  const int b = blockIdx.y * 64 + lane;
  const int ho = hw / WO2, wo = hw - ho * WO2;

  for (int i = threadIdx.x; i < P2 * O2; i += 256) {
    const int p = i >> 4, o = i & 15;
    ws[i] = w2t[((size_t)p * HW2 + hw) * O2 + o];
  }
  __syncthreads();

  float acc[4];
#pragma unroll
  for (int oi = 0; oi < 4; ++oi) acc[oi] = b2[(og * 4 + oi) * HW2 + hw];

  const float* xb = h1 + (size_t)b * IMG2 + (size_t)(ho * 4) * W2c + wo * 4;

#pragma unroll 1
  for (int c = 0; c < C2; ++c) {
    // ---- issue all 18 x loads for this c (6 kh x 3 float2)
    float xv[6][6];
#pragma unroll
    for (int kh = 0; kh < 6; ++kh) {
      const float* xr = xb + c * PLANE2 + kh * W2c;
      const float2 a0 = *reinterpret_cast<const float2*>(xr);
      const float2 a1 = *reinterpret_cast<const float2*>(xr + 2);
      const float2 a2 = *reinterpret_cast<const float2*>(xr + 4);
      xv[kh][0] = a0.x; xv[kh][1] = a0.y;
      xv[kh][2] = a1.x; xv[kh][3] = a1.y;
      xv[kh][4] = a2.x; xv[kh][5] = a2.y;
    }
    __builtin_amdgcn_sched_barrier(0);
    // ---- consume from LDS weights
#pragma unroll
    for (int kh = 0; kh < 6; ++kh) {
#pragma unroll
      for (int kw = 0; kw < 6; ++kw) {
        const int p = (c * 6 + kh) * 6 + kw;
        const float4 wv = *reinterpret_cast<const float4*>(&ws[p * O2 + og * 4]);
        acc[0] = fmaf(xv[kh][kw], wv.x, acc[0]);
        acc[1] = fmaf(xv[kh][kw], wv.y, acc[1]);
        acc[2] = fmaf(xv[kh][kw], wv.z, acc[2]);
        acc[3] = fmaf(xv[kh][kw], wv.w, acc[3]);
      }
    }
  }

#pragma unroll
  for (int oi = 0; oi < 4; ++oi) {
    h2[((size_t)b * O2 + og * 4 + oi) * HW2 + hw] = fmaxf(acc[oi], 0.f);
  }
}

// ---- fused head: maxpool(2) -> FC1+ReLU -> FC2 -> softmax.
// one block (512 thr = 8 waves) per batch row; all intermediates in LDS.
__global__ __launch_bounds__(512) void head_kernel(const float* __restrict__ h2,
                                                   const float* __restrict__ fc1w,
                                                   const float* __restrict__ fc1b,
                                                   const float* __restrict__ fc2w,
                                                   const float* __restrict__ fc2b,
                                                   float* __restrict__ out) {
  __shared__ __align__(16) float sp[NPOOL];
  __shared__ __align__(16) float sh[N1];
  __shared__ float sl[N2];
  __shared__ float red[2];
  const int b = blockIdx.x;
  const int tid = threadIdx.x;

  if (tid < NPOOL) {
    const int o = tid / 30, r2 = tid - o * 30;
    const int i = r2 / 5, j = r2 - i * 5;
    const float* base = h2 + ((size_t)(b * O2 + o) * HO2 + 2 * i) * WO2 + 2 * j;
    sp[tid] = fmaxf(fmaxf(base[0], base[1]), fmaxf(base[WO2], base[WO2 + 1]));
  }
  __syncthreads();

  const int wv = tid >> 6, ln = tid & 63;
  const float4* sp4 = reinterpret_cast<const float4*>(sp);
  for (int n = wv; n < N1; n += 8) {
    const float4* wr = reinterpret_cast<const float4*>(fc1w + (size_t)n * NPOOL);
    float4 a = wr[ln], p = sp4[ln];
    float s = fmaf(a.x, p.x, fmaf(a.y, p.y, fmaf(a.z, p.z, a.w * p.w)));
    if (ln < 56) {
      float4 a2 = wr[64 + ln], p2 = sp4[64 + ln];
      s = fmaf(a2.x, p2.x, fmaf(a2.y, p2.y, fmaf(a2.z, p2.z, fmaf(a2.w, p2.w, s))));
    }
#pragma unroll
    for (int off = 32; off > 0; off >>= 1) s += __shfl_xor(s, off, 64);
    if (ln == 0) sh[n] = fmaxf(s + fc1b[n], 0.f);
  }
  __syncthreads();

  const float4* sh4 = reinterpret_cast<const float4*>(sh);
  for (int n = wv; n < N2; n += 8) {
    const float4* wr = reinterpret_cast<const float4*>(fc2w + (size_t)n * N1);
    float4 a = wr[ln], p = sh4[ln];
    float s = fmaf(a.x, p.x, fmaf(a.y, p.y, fmaf(a.z, p.z, a.w * p.w)));
    if (ln < 11) {
      float4 a2 = wr[64 + ln], p2 = sh4[64 + ln];
      s = fmaf(a2.x, p2.x, fmaf(a2.y, p2.y, fmaf(a2.z, p2.z, fmaf(a2.w, p2.w, s))));
    }
#pragma unroll
    for (int off = 32; off > 0; off >>= 1) s += __shfl_xor(s, off, 64);
    if (ln == 0) sl[n] = s + fc2b[n];
  }
  __syncthreads();

  if (wv == 0) {
    float m = fmaxf(fmaxf(sl[ln], sl[ln + 64]), sl[ln + 128]);
    if (ln < 8) m = fmaxf(m, sl[192 + ln]);
#pragma unroll
    for (int off = 32; off > 0; off >>= 1) m = fmaxf(m, __shfl_xor(m, off, 64));
    if (ln == 0) red[0] = m;
  }
  __syncthreads();
  const float mx = red[0];
  if (tid < N2) sl[tid] = expf(sl[tid] - mx);
  __syncthreads();
  if (wv == 0) {
    float s = sl[ln] + sl[ln + 64] + sl[ln + 128] + (ln < 8 ? sl[192 + ln] : 0.f);
#pragma unroll
    for (int off = 32; off > 0; off >>= 1) s += __shfl_xor(s, off, 64);
    if (ln == 0) red[1] = s;
  }
  __syncthreads();
  if (tid < N2) out[(size_t)b * N2 + tid] = sl[tid] / red[1];
}

}  // namespace

extern "C" void kernel_launch(void* const* d_in, const int* in_sizes, int n_in,
                              void* d_out, int out_size, void* d_ws, size_t ws_size,
                              hipStream_t stream) {
  const float* x     = (const float*)d_in[0];
  const float* w1    = (const float*)d_in[1];
  const float* b1    = (const float*)d_in[2];
  const float* w2    = (const float*)d_in[3];
  const float* b2    = (const float*)d_in[4];
  const float* fc1_w = (const float*)d_in[5];
  const float* fc1_b = (const float*)d_in[6];
  const float* fc2_w = (const float*)d_in[7];
  const float* fc2_b = (const float*)d_in[8];
  float* out = (float*)d_out;

  float* ws  = (float*)d_ws;
  float* w1t = ws;                                  // 2,052,864 f
  float* w2t = w1t + (size_t)O1 * P1 * HW1;         //   599,040 f
  float* h1  = w2t + (size_t)O2 * P2 * HW2;         // 4,866,048 f
  float* h2  = h1 + (size_t)BATCH * O1 * HW1;       //   532,480 f

  wt1_kernel<<<(P1 * HW1 + 255) / 256, 256, 0, stream>>>(w1, w1t);
  wt2_kernel<<<(P2 * HW2 + 255) / 256, 256, 0, stream>>>(w2, w2t);
  lc1_kernel<<<dim3(HO1, BATCH / NB1), 192, 0, stream>>>(x, w1t, b1, h1);
  lc2_kernel<<<dim3(HW2, 4), 256, 0, stream>>>(h1, w2t, b2, h2);
  head_kernel<<<BATCH, 512, 0, stream>>>(h2, fc1_w, fc1_b, fc2_w, fc2_b, out);
}

// Round 9
// 167.920 us; speedup vs baseline: 1.3081x; 1.3081x over previous
//
#include <hip/hip_runtime.h>
#include <cmath>

namespace {

constexpr int BATCH = 256;
// layer 1
constexpr int C1 = 3, H1 = 218, W1 = 178;
constexpr int IMG1 = C1 * H1 * W1;            // 116412
constexpr int PLANE1 = H1 * W1;               // 38804
constexpr int O1 = 8, HO1 = 54, WO1 = 44;
constexpr int HW1 = HO1 * WO1;                // 2376
constexpr int P1 = C1 * 36;                   // 108
// layer 2
constexpr int C2 = 8, H2c = 54, W2c = 44;
constexpr int O2 = 16, HO2 = 13, WO2 = 10;
constexpr int HW2 = HO2 * WO2;                // 130
constexpr int P2 = C2 * 36;                   // 288
// head
constexpr int NPOOL = 480;                    // 16*6*5
constexpr int N1 = 300, N2 = 200;

// lc1 tiling: block = (1 ho row x 44 wo) x 16 batches, 192 threads.
constexpr int NB1 = 16;                       // batches per block
constexpr int XROW = 180;                     // padded LDS row (178+2), 16B-aligned row base
constexpr int XCHUNK = NB1 * XROW;            // 2880 floats per x chunk buffer
constexpr int WCHUNK = 2 * 6 * 44 * 4;        // 2112 floats per w chunk buffer

// ---- transpose w1 (O1,P1,HW1) -> (P1*HW1, O1)
__global__ __launch_bounds__(256) void wt1_kernel(const float* __restrict__ w,
                                                  float* __restrict__ wt) {
  const int idx = blockIdx.x * 256 + threadIdx.x;   // p*HW1 + hw
  if (idx >= P1 * HW1) return;
  float v[O1];
#pragma unroll
  for (int o = 0; o < O1; ++o) v[o] = w[(size_t)o * (P1 * HW1) + idx];
  float4* dst = reinterpret_cast<float4*>(wt + (size_t)idx * O1);
  dst[0] = make_float4(v[0], v[1], v[2], v[3]);
  dst[1] = make_float4(v[4], v[5], v[6], v[7]);
}

// ---- transpose w2 (O2,P2,HW2) -> (P2*HW2, O2)
__global__ __launch_bounds__(256) void wt2_kernel(const float* __restrict__ w,
                                                  float* __restrict__ wt) {
  const int idx = blockIdx.x * 256 + threadIdx.x;   // p*HW2 + hw
  if (idx >= P2 * HW2) return;
  float v[O2];
#pragma unroll
  for (int o = 0; o < O2; ++o) v[o] = w[(size_t)o * (P2 * HW2) + idx];
  float4* dst = reinterpret_cast<float4*>(wt + (size_t)idx * O2);
  dst[0] = make_float4(v[0], v[1], v[2], v[3]);
  dst[1] = make_float4(v[4], v[5], v[6], v[7]);
  dst[2] = make_float4(v[8], v[9], v[10], v[11]);
  dst[3] = make_float4(v[12], v[13], v[14], v[15]);
}

// ---- locally-connected layer 1 + ReLU, LDS-staged, single-barrier pipeline.
// Round-8 post-mortem: 2 barriers/chunk + vmcnt(0)-stalling writes + 96 FMA
// of compute = 2.9k cy/chunk. Fix: per chunk do
//   barrier -> WRITE(k+1) (regs drained by barrier: zero-stall)
//           -> issue LOAD(k+2) -> sched_barrier -> COMPUTE(k) [192 FMA]
// Double-buffered LDS (write buf (k+1)&1 while reading k&1 is barrier-safe).
// NB=16 halves w re-staging; output h1 is (C,H,W,B) so lc2 reads coalesce.
__global__ __launch_bounds__(192) void lc1_kernel(const float* __restrict__ x,
                                                  const float* __restrict__ w1t,
                                                  const float* __restrict__ b1,
                                                  float* __restrict__ h1t) {
  __shared__ __align__(16) float xlds[2][XCHUNK];   // 23040 B
  __shared__ __align__(16) float wlds[2][WCHUNK];   // 16896 B
  const int t = threadIdx.x;
  const int ho = blockIdx.x;
  const int bg = blockIdx.y * NB1;
  const int bslot = t / 44;               // 0..3 for t<176
  const int wo = t - bslot * 44;
  const bool act = t < 176;

  // chunk-invariant staging coordinates (hoisted: no div/mod in the loop)
  int xgoff[8], xloff[8];
#pragma unroll
  for (int s = 0; s < 8; ++s) {
    int i = t + s * 192; i = i < 1423 ? i : 1423;   // 16 rows x 89 float2
    const int b_ = i / 89, c2 = i - b_ * 89;
    xgoff[s] = (bg + b_) * IMG1 + c2 * 2;
    xloff[s] = b_ * XROW + c2 * 2;
  }
  int wgoff[3], wloff[3];
#pragma unroll
  for (int s = 0; s < 3; ++s) {
    int i = t + s * 192; i = i < 527 ? i : 527;     // 6 kw x 88 float4
    const int kw_ = i / 88, r_ = i - kw_ * 88;
    wgoff[s] = kw_ * (HW1 * 8) + r_ * 4;
    wloff[s] = ((r_ & 1) * 6 + kw_) * 44 + (r_ >> 1);
  }

  float acc[4][O1];
  if (act) {
    const int hw = ho * WO1 + wo;
#pragma unroll
    for (int o = 0; o < O1; ++o) {
      const float bv = b1[o * HW1 + hw];
#pragma unroll
      for (int j = 0; j < 4; ++j) acc[j][o] = bv;
    }
  }

  float2 xr0[8], xr1[8];
  float4 wr0[3], wr1[3];

#define LC1_LOAD(K, XR, WR)                                                    \
  do {                                                                         \
    const int c_ = (K) / 6, kh_ = (K) - c_ * 6;                                \
    const int xo_ = c_ * PLANE1 + (ho * 4 + kh_) * W1;                         \
    _Pragma("unroll") for (int s = 0; s < 8; ++s)                              \
        XR[s] = *reinterpret_cast<const float2*>(x + xgoff[s] + xo_);          \
    const int wo_ = ((K) * 6 * HW1 + ho * WO1) * 8;                            \
    _Pragma("unroll") for (int s = 0; s < 3; ++s)                              \
        WR[s] = *reinterpret_cast<const float4*>(w1t + wo_ + wgoff[s]);        \
  } while (0)

#define LC1_WRITE(BUF, XR, WR)                                                 \
  do {                                                                         \
    _Pragma("unroll") for (int s = 0; s < 8; ++s)                              \
        *reinterpret_cast<float2*>(&xlds[BUF][xloff[s]]) = XR[s];              \
    _Pragma("unroll") for (int s = 0; s < 3; ++s)                              \
        reinterpret_cast<float4*>(wlds[BUF])[wloff[s]] = WR[s];                \
  } while (0)

  // prologue: chunk0 staged, chunk1 in flight
  LC1_LOAD(0, xr0, wr0);
  LC1_LOAD(1, xr1, wr1);
  LC1_WRITE(0, xr0, wr0);          // counted wait: only chunk0's loads

#pragma unroll
  for (int k = 0; k < 18; ++k) {
    __syncthreads();               // buf k&1 visible; all in-flight loads drained
    if (k < 17) {                  // write chunk k+1 (regs ready, zero stall)
      if ((k + 1) & 1) LC1_WRITE(1, xr1, wr1);
      else             LC1_WRITE(0, xr0, wr0);
    }
    if (k < 16) {                  // issue chunk k+2 loads; land during compute
      if (k & 1) LC1_LOAD(k + 2, xr1, wr1);
      else       LC1_LOAD(k + 2, xr0, wr0);
    }
    __builtin_amdgcn_sched_barrier(0);
    if (act) {
      const float* xb = xlds[k & 1];
      const float4* wb = reinterpret_cast<const float4*>(wlds[k & 1]);
      float xw[4][6];
#pragma unroll
      for (int jj = 0; jj < 4; ++jj) {
        const int xoff = (bslot * 4 + jj) * XROW + wo * 4;
        const float4 xa = *reinterpret_cast<const float4*>(&xb[xoff]);
        const float2 xt = *reinterpret_cast<const float2*>(&xb[xoff + 4]);
        xw[jj][0] = xa.x; xw[jj][1] = xa.y; xw[jj][2] = xa.z;
        xw[jj][3] = xa.w; xw[jj][4] = xt.x; xw[jj][5] = xt.y;
      }
#pragma unroll
      for (int kw = 0; kw < 6; ++kw) {
        const float4 wA = wb[kw * 44 + wo];
        const float4 wB = wb[(6 + kw) * 44 + wo];
#pragma unroll
        for (int jj = 0; jj < 4; ++jj) {
          const float xs = xw[jj][kw];
          acc[jj][0] = fmaf(xs, wA.x, acc[jj][0]);
          acc[jj][1] = fmaf(xs, wA.y, acc[jj][1]);
          acc[jj][2] = fmaf(xs, wA.z, acc[jj][2]);
          acc[jj][3] = fmaf(xs, wA.w, acc[jj][3]);
          acc[jj][4] = fmaf(xs, wB.x, acc[jj][4]);
          acc[jj][5] = fmaf(xs, wB.y, acc[jj][5]);
          acc[jj][6] = fmaf(xs, wB.z, acc[jj][6]);
          acc[jj][7] = fmaf(xs, wB.w, acc[jj][7]);
        }
      }
    }
  }
#undef LC1_LOAD
#undef LC1_WRITE

  if (act) {
    const int hw = ho * WO1 + wo;
#pragma unroll
    for (int o = 0; o < O1; ++o) {
      const float4 v = make_float4(fmaxf(acc[0][o], 0.f), fmaxf(acc[1][o], 0.f),
                                   fmaxf(acc[2][o], 0.f), fmaxf(acc[3][o], 0.f));
      // h1t layout (C2=8, H=54, W=44, B=256): 4 batches per float4 store;
      // the 4 bslots of a block fully cover each 64B line -> clean writeback.
      *reinterpret_cast<float4*>(h1t + ((size_t)o * HW1 + hw) * BATCH + bg +
                                 bslot * 4) = v;
    }
  }
}

// ---- locally-connected layer 2 + ReLU, GEMM-ified per spatial location.
// h1t is batch-contiguous -> every x load is a coalesced 256B wave read.
__global__ __launch_bounds__(256) void lc2_kernel(const float* __restrict__ h1t,
                                                  const float* __restrict__ w2t,
                                                  const float* __restrict__ b2,
                                                  float* __restrict__ h2) {
  __shared__ float ws[P2 * O2];                 // 18432 B
  const int hw = blockIdx.x;
  const int lane = threadIdx.x & 63;
  const int og = threadIdx.x >> 6;
  const int b = blockIdx.y * 64 + lane;
  const int ho = hw / WO2, wo = hw - ho * WO2;

  for (int i = threadIdx.x; i < P2 * O2; i += 256) {
    const int p = i >> 4, o = i & 15;
    ws[i] = w2t[((size_t)p * HW2 + hw) * O2 + o];
  }
  __syncthreads();

  float acc[4];
#pragma unroll
  for (int oi = 0; oi < 4; ++oi) acc[oi] = b2[(og * 4 + oi) * HW2 + hw];

#pragma unroll 1
  for (int c = 0; c < C2; ++c) {
    const float* bc =
        h1t + ((size_t)(c * H2c + ho * 4) * W2c + wo * 4) * BATCH + b;
    float xv[6][6];
#pragma unroll
    for (int kh = 0; kh < 6; ++kh)
#pragma unroll
      for (int kw = 0; kw < 6; ++kw)
        xv[kh][kw] = bc[(size_t)(kh * W2c + kw) * BATCH];
    __builtin_amdgcn_sched_barrier(0);
#pragma unroll
    for (int kh = 0; kh < 6; ++kh) {
#pragma unroll
      for (int kw = 0; kw < 6; ++kw) {
        const int p = (c * 6 + kh) * 6 + kw;
        const float4 wv = *reinterpret_cast<const float4*>(&ws[p * O2 + og * 4]);
        acc[0] = fmaf(xv[kh][kw], wv.x, acc[0]);
        acc[1] = fmaf(xv[kh][kw], wv.y, acc[1]);
        acc[2] = fmaf(xv[kh][kw], wv.z, acc[2]);
        acc[3] = fmaf(xv[kh][kw], wv.w, acc[3]);
      }
    }
  }

#pragma unroll
  for (int oi = 0; oi < 4; ++oi) {
    h2[((size_t)b * O2 + og * 4 + oi) * HW2 + hw] = fmaxf(acc[oi], 0.f);
  }
}

// ---- fused head: maxpool(2) -> FC1+ReLU -> FC2 -> softmax.
__global__ __launch_bounds__(512) void head_kernel(const float* __restrict__ h2,
                                                   const float* __restrict__ fc1w,
                                                   const float* __restrict__ fc1b,
                                                   const float* __restrict__ fc2w,
                                                   const float* __restrict__ fc2b,
                                                   float* __restrict__ out) {
  __shared__ __align__(16) float sp[NPOOL];
  __shared__ __align__(16) float sh[N1];
  __shared__ float sl[N2];
  __shared__ float red[2];
  const int b = blockIdx.x;
  const int tid = threadIdx.x;

  if (tid < NPOOL) {
    const int o = tid / 30, r2 = tid - o * 30;
    const int i = r2 / 5, j = r2 - i * 5;
    const float* base = h2 + ((size_t)(b * O2 + o) * HO2 + 2 * i) * WO2 + 2 * j;
    sp[tid] = fmaxf(fmaxf(base[0], base[1]), fmaxf(base[WO2], base[WO2 + 1]));
  }
  __syncthreads();

  const int wv = tid >> 6, ln = tid & 63;
  const float4* sp4 = reinterpret_cast<const float4*>(sp);
  for (int n = wv; n < N1; n += 8) {
    const float4* wr = reinterpret_cast<const float4*>(fc1w + (size_t)n * NPOOL);
    float4 a = wr[ln], p = sp4[ln];
    float s = fmaf(a.x, p.x, fmaf(a.y, p.y, fmaf(a.z, p.z, a.w * p.w)));
    if (ln < 56) {
      float4 a2 = wr[64 + ln], p2 = sp4[64 + ln];
      s = fmaf(a2.x, p2.x, fmaf(a2.y, p2.y, fmaf(a2.z, p2.z, fmaf(a2.w, p2.w, s))));
    }
#pragma unroll
    for (int off = 32; off > 0; off >>= 1) s += __shfl_xor(s, off, 64);
    if (ln == 0) sh[n] = fmaxf(s + fc1b[n], 0.f);
  }
  __syncthreads();

  const float4* sh4 = reinterpret_cast<const float4*>(sh);
  for (int n = wv; n < N2; n += 8) {
    const float4* wr = reinterpret_cast<const float4*>(fc2w + (size_t)n * N1);
    float4 a = wr[ln], p = sh4[ln];
    float s = fmaf(a.x, p.x, fmaf(a.y, p.y, fmaf(a.z, p.z, a.w * p.w)));
    if (ln < 11) {
      float4 a2 = wr[64 + ln], p2 = sh4[64 + ln];
      s = fmaf(a2.x, p2.x, fmaf(a2.y, p2.y, fmaf(a2.z, p2.z, fmaf(a2.w, p2.w, s))));
    }
#pragma unroll
    for (int off = 32; off > 0; off >>= 1) s += __shfl_xor(s, off, 64);
    if (ln == 0) sl[n] = s + fc2b[n];
  }
  __syncthreads();

  if (wv == 0) {
    float m = fmaxf(fmaxf(sl[ln], sl[ln + 64]), sl[ln + 128]);
    if (ln < 8) m = fmaxf(m, sl[192 + ln]);
#pragma unroll
    for (int off = 32; off > 0; off >>= 1) m = fmaxf(m, __shfl_xor(m, off, 64));
    if (ln == 0) red[0] = m;
  }
  __syncthreads();
  const float mx = red[0];
  if (tid < N2) sl[tid] = expf(sl[tid] - mx);
  __syncthreads();
  if (wv == 0) {
    float s = sl[ln] + sl[ln + 64] + sl[ln + 128] + (ln < 8 ? sl[192 + ln] : 0.f);
#pragma unroll
    for (int off = 32; off > 0; off >>= 1) s += __shfl_xor(s, off, 64);
    if (ln == 0) red[1] = s;
  }
  __syncthreads();
  if (tid < N2) out[(size_t)b * N2 + tid] = sl[tid] / red[1];
}

}  // namespace

extern "C" void kernel_launch(void* const* d_in, const int* in_sizes, int n_in,
                              void* d_out, int out_size, void* d_ws, size_t ws_size,
                              hipStream_t stream) {
  const float* x     = (const float*)d_in[0];
  const float* w1    = (const float*)d_in[1];
  const float* b1    = (const float*)d_in[2];
  const float* w2    = (const float*)d_in[3];
  const float* b2    = (const float*)d_in[4];
  const float* fc1_w = (const float*)d_in[5];
  const float* fc1_b = (const float*)d_in[6];
  const float* fc2_w = (const float*)d_in[7];
  const float* fc2_b = (const float*)d_in[8];
  float* out = (float*)d_out;

  float* ws  = (float*)d_ws;
  float* w1t = ws;                                  // 2,052,864 f
  float* w2t = w1t + (size_t)O1 * P1 * HW1;         //   599,040 f
  float* h1t = w2t + (size_t)O2 * P2 * HW2;         // 4,866,048 f  (C,H,W,B)
  float* h2  = h1t + (size_t)BATCH * O1 * HW1;      //   532,480 f

  wt1_kernel<<<(P1 * HW1 + 255) / 256, 256, 0, stream>>>(w1, w1t);
  wt2_kernel<<<(P2 * HW2 + 255) / 256, 256, 0, stream>>>(w2, w2t);
  lc1_kernel<<<dim3(HO1, BATCH / NB1), 192, 0, stream>>>(x, w1t, b1, h1t);
  lc2_kernel<<<dim3(HW2, 4), 256, 0, stream>>>(h1t, w2t, b2, h2);
  head_kernel<<<BATCH, 512, 0, stream>>>(h2, fc1_w, fc1_b, fc2_w, fc2_b, out);
}